// Round 1
// baseline (3081.281 us; speedup 1.0000x reference)
//
#include <hip/hip_runtime.h>
#include <hip/hip_bf16.h>
#include <math.h>

#define RR 64
#define CC 32
#define HH 128
#define FEATN 96
#define NPTS (4*262144)

// ws layout (floats):
// [0]      Tplanes: 3*64*64*32 = 393216   (channel-last: [p][y][x][c])
// [393216] dW1t [96][128] = 12288          (column-major: [k][j])
// [405504] rW1t [96][128] = 12288
// total 417792 floats = 1.67 MB

__global__ void transpose_kernel(const float* __restrict__ planes,
                                 const float* __restrict__ dW1,
                                 const float* __restrict__ rW1,
                                 float* __restrict__ ws) {
    int tid = blockIdx.x * blockDim.x + threadIdx.x;
    if (tid < 3 * CC * RR * RR) {
        int x = tid % RR;
        int y = (tid / RR) % RR;
        int c = (tid / (RR * RR)) % CC;
        int p = tid / (CC * RR * RR);
        ws[((p * RR + y) * RR + x) * CC + c] = planes[tid];
    }
    if (tid < HH * FEATN) {
        int k = tid % FEATN;
        int j = tid / FEATN;
        ws[393216 + k * HH + j] = dW1[tid];
        ws[405504 + k * HH + j] = rW1[tid];
    }
}

__global__ __launch_bounds__(256, 1)
void nerf_kernel(const float* __restrict__ points,
                 const float* __restrict__ ws,
                 const float* __restrict__ db1,
                 const float* __restrict__ dW2, const float* __restrict__ db2,
                 const float* __restrict__ dW3, const float* __restrict__ db3,
                 const float* __restrict__ rb1,
                 const float* __restrict__ rW2, const float* __restrict__ rb2,
                 float* __restrict__ rgb_out, float* __restrict__ den_out) {
    int i = blockIdx.x * blockDim.x + threadIdx.x;
    if (i >= NPTS) return;

    float x = points[i * 3 + 0];
    float y = points[i * 3 + 1];
    float z = points[i * 3 + 2];

    const float* T    = ws;
    const float* dW1t = ws + 393216;
    const float* rW1t = ws + 405504;

    // plane0:(x,y)  plane1:(x,z)  plane2:(y,z)
    float cxa[3] = {x, x, y};
    float cya[3] = {y, z, z};
    int   b00[3], b01[3], b10[3], b11[3];
    float w00[3], w01[3], w10[3], w11[3];
    #pragma unroll
    for (int p = 0; p < 3; ++p) {
        float ix = (cxa[p] + 1.0f) * 0.5f * (float)(RR - 1);
        float iy = (cya[p] + 1.0f) * 0.5f * (float)(RR - 1);
        ix = fminf(fmaxf(ix, 0.0f), (float)(RR - 1));
        iy = fminf(fmaxf(iy, 0.0f), (float)(RR - 1));
        int x0 = (int)floorf(ix);
        int y0 = (int)floorf(iy);
        int x1 = min(x0 + 1, RR - 1);
        int y1 = min(y0 + 1, RR - 1);
        float wx = ix - (float)x0;
        float wy = iy - (float)y0;
        w00[p] = (1.0f - wx) * (1.0f - wy);
        w01[p] = wx * (1.0f - wy);
        w10[p] = (1.0f - wx) * wy;
        w11[p] = wx * wy;
        int pb = p * RR * RR;
        b00[p] = (pb + y0 * RR + x0) * CC;
        b01[p] = (pb + y0 * RR + x1) * CC;
        b10[p] = (pb + y1 * RR + x0) * CC;
        b11[p] = (pb + y1 * RR + x1) * CC;
    }

    // accumulators for layer 1 of both MLPs (init = bias)
    float hd[HH];
    float hr[HH];
    #pragma unroll
    for (int j = 0; j < HH; ++j) {
        hd[j] = db1[j];
        hr[j] = rb1[j];
    }

    // fused sampling + layer 1 (feat never materialized as an array)
    #pragma unroll
    for (int p = 0; p < 3; ++p) {
        for (int c4 = 0; c4 < CC; c4 += 4) {   // runtime loop
            float4 v00 = *reinterpret_cast<const float4*>(T + b00[p] + c4);
            float4 v01 = *reinterpret_cast<const float4*>(T + b01[p] + c4);
            float4 v10 = *reinterpret_cast<const float4*>(T + b10[p] + c4);
            float4 v11 = *reinterpret_cast<const float4*>(T + b11[p] + c4);
            float f[4];
            f[0] = w00[p] * v00.x + w01[p] * v01.x + w10[p] * v10.x + w11[p] * v11.x;
            f[1] = w00[p] * v00.y + w01[p] * v01.y + w10[p] * v10.y + w11[p] * v11.y;
            f[2] = w00[p] * v00.z + w01[p] * v01.z + w10[p] * v10.z + w11[p] * v11.z;
            f[3] = w00[p] * v00.w + w01[p] * v01.w + w10[p] * v10.w + w11[p] * v11.w;
            const float* wd = dW1t + (p * CC + c4) * HH;
            const float* wr = rW1t + (p * CC + c4) * HH;
            #pragma unroll
            for (int u = 0; u < 4; ++u) {
                #pragma unroll
                for (int j = 0; j < HH; j += 4) {
                    float4 wdv = *reinterpret_cast<const float4*>(wd + u * HH + j);
                    float4 wrv = *reinterpret_cast<const float4*>(wr + u * HH + j);
                    hd[j + 0] = fmaf(f[u], wdv.x, hd[j + 0]);
                    hd[j + 1] = fmaf(f[u], wdv.y, hd[j + 1]);
                    hd[j + 2] = fmaf(f[u], wdv.z, hd[j + 2]);
                    hd[j + 3] = fmaf(f[u], wdv.w, hd[j + 3]);
                    hr[j + 0] = fmaf(f[u], wrv.x, hr[j + 0]);
                    hr[j + 1] = fmaf(f[u], wrv.y, hr[j + 1]);
                    hr[j + 2] = fmaf(f[u], wrv.z, hr[j + 2]);
                    hr[j + 3] = fmaf(f[u], wrv.w, hr[j + 3]);
                }
            }
        }
    }

    // rgb head first (kills hr early): rgb = sigmoid(relu(hr) @ rW2.T + rb2)
    float racc0 = rb2[0], racc1 = rb2[1], racc2 = rb2[2];
    #pragma unroll
    for (int j = 0; j < HH; j += 4) {
        float4 w0 = *reinterpret_cast<const float4*>(rW2 + 0 * HH + j);
        float4 w1 = *reinterpret_cast<const float4*>(rW2 + 1 * HH + j);
        float4 w2 = *reinterpret_cast<const float4*>(rW2 + 2 * HH + j);
        float a0 = fmaxf(hr[j + 0], 0.0f);
        float a1 = fmaxf(hr[j + 1], 0.0f);
        float a2 = fmaxf(hr[j + 2], 0.0f);
        float a3 = fmaxf(hr[j + 3], 0.0f);
        racc0 = fmaf(a0, w0.x, racc0); racc1 = fmaf(a0, w1.x, racc1); racc2 = fmaf(a0, w2.x, racc2);
        racc0 = fmaf(a1, w0.y, racc0); racc1 = fmaf(a1, w1.y, racc1); racc2 = fmaf(a1, w2.y, racc2);
        racc0 = fmaf(a2, w0.z, racc0); racc1 = fmaf(a2, w1.z, racc1); racc2 = fmaf(a2, w2.z, racc2);
        racc0 = fmaf(a3, w0.w, racc0); racc1 = fmaf(a3, w1.w, racc1); racc2 = fmaf(a3, w2.w, racc2);
    }
    rgb_out[i * 3 + 0] = 1.0f / (1.0f + expf(-racc0));
    rgb_out[i * 3 + 1] = 1.0f / (1.0f + expf(-racc1));
    rgb_out[i * 3 + 2] = 1.0f / (1.0f + expf(-racc2));

    // density layers 2+3 fused: h2 never materialized
    #pragma unroll
    for (int j = 0; j < HH; ++j) hd[j] = fmaxf(hd[j], 0.0f);

    float dacc = db3[0];
    for (int j = 0; j < HH; ++j) {   // runtime loop
        const float* w = dW2 + j * HH;
        float a0 = 0.0f, a1 = 0.0f, a2 = 0.0f, a3 = 0.0f;
        #pragma unroll
        for (int k = 0; k < HH; k += 4) {
            float4 wv = *reinterpret_cast<const float4*>(w + k);
            a0 = fmaf(hd[k + 0], wv.x, a0);
            a1 = fmaf(hd[k + 1], wv.y, a1);
            a2 = fmaf(hd[k + 2], wv.z, a2);
            a3 = fmaf(hd[k + 3], wv.w, a3);
        }
        float acc = db2[j] + ((a0 + a1) + (a2 + a3));
        dacc = fmaf(dW3[j], fmaxf(acc, 0.0f), dacc);
    }
    // softplus = max(x,0) + log1p(exp(-|x|))
    den_out[i] = fmaxf(dacc, 0.0f) + log1pf(expf(-fabsf(dacc)));
}

extern "C" void kernel_launch(void* const* d_in, const int* in_sizes, int n_in,
                              void* d_out, int out_size, void* d_ws, size_t ws_size,
                              hipStream_t stream) {
    const float* points = (const float*)d_in[0];
    const float* planes = (const float*)d_in[1];
    const float* dW1    = (const float*)d_in[2];
    const float* db1    = (const float*)d_in[3];
    const float* dW2    = (const float*)d_in[4];
    const float* db2    = (const float*)d_in[5];
    const float* dW3    = (const float*)d_in[6];
    const float* db3    = (const float*)d_in[7];
    const float* rW1    = (const float*)d_in[8];
    const float* rb1    = (const float*)d_in[9];
    const float* rW2    = (const float*)d_in[10];
    const float* rb2    = (const float*)d_in[11];

    float* out     = (float*)d_out;
    float* rgb_out = out;                 // 4*262144*3 floats
    float* den_out = out + 3145728;       // 4*262144*1 floats
    float* ws      = (float*)d_ws;

    transpose_kernel<<<1536, 256, 0, stream>>>(planes, dW1, rW1, ws);
    nerf_kernel<<<4096, 256, 0, stream>>>(points, ws, db1, dW2, db2, dW3, db3,
                                          rb1, rW2, rb2, rgb_out, den_out);
}

// Round 2
// 1561.070 us; speedup vs baseline: 1.9738x; 1.9738x over previous
//
#include <hip/hip_runtime.h>
#include <hip/hip_bf16.h>
#include <math.h>

#define RR 64
#define CC 32
#define NPTS (4*262144)

typedef __attribute__((ext_vector_type(8))) short short8;
typedef __attribute__((ext_vector_type(4))) float f32x4;

union FragS { ushort s[8]; short8 v; uint32_t u[4]; };
union BH { __hip_bfloat16 h; ushort u; };

static __device__ inline ushort f2bf(float x) {
    BH b; b.h = __float2bfloat16(x); return b.u;
}
static __device__ inline uint32_t pk2(float a, float b) {
    return (uint32_t)f2bf(a) | ((uint32_t)f2bf(b) << 16);
}

// ws layout:
//   float  Pcl[3*64*64*32]      @ 0            (channel-last fp32 planes [p][y][x][ch])
//   ushort W1T[16*3*64*8]       @ 393216 f     (layer1 A-frag table, [nt][p][lane][e], bf16)
//   ushort W2T[8*4*64*8]        after W1T      (layer2 A-frag table, [nt2][kt2][lane][e])
//   float  BC[256]              after W2T      (bias concat [db1|rb1])

__global__ void prepass(const float* __restrict__ planes,
                        const float* __restrict__ dW1, const float* __restrict__ rW1,
                        const float* __restrict__ dW2,
                        const float* __restrict__ db1, const float* __restrict__ rb1,
                        float* __restrict__ ws) {
    int tid = blockIdx.x * blockDim.x + threadIdx.x;
    ushort* W1T = (ushort*)(ws + 393216);
    ushort* W2T = W1T + 24576;
    float*  BC  = (float*)(W2T + 16384);

    if (tid < 3 * CC * RR * RR) {
        int x = tid % RR, y = (tid / RR) % RR, ch = (tid / (RR * RR)) % CC, p = tid / (CC * RR * RR);
        ws[((p * RR + y) * RR + x) * CC + ch] = planes[tid];
    }
    if (tid < 24576) {   // W1T: tid = ((nt*3+p)*64 + l)*8 + e
        int e = tid & 7, l = (tid >> 3) & 63, rem = tid >> 9;
        int p = rem % 3, nt = rem / 3;
        int j = nt * 16 + (l & 15);
        int k = p * 32 + (l >> 4) * 8 + e;
        float v = (j < 128) ? dW1[j * 96 + k] : rW1[(j - 128) * 96 + k];
        W1T[tid] = f2bf(v);
    }
    if (tid < 16384) {   // W2T: tid = ((nt2*4+kt2)*64 + l)*8 + e
        int e = tid & 7, l = (tid >> 3) & 63, rem = tid >> 9;
        int kt2 = rem & 3, nt2 = rem >> 2;
        int j2 = nt2 * 16 + (l & 15);
        int k = kt2 * 32 + (l >> 4) * 8 + e;
        W2T[tid] = f2bf(dW2[j2 * 128 + k]);
    }
    if (tid < 256) {
        BC[tid] = (tid < 128) ? db1[tid] : rb1[tid - 128];
    }
}

__global__ __launch_bounds__(256, 3)
void nerf_mfma(const float* __restrict__ points, const float* __restrict__ ws,
               const float* __restrict__ db2, const float* __restrict__ db3,
               const float* __restrict__ dW3,
               const float* __restrict__ rW2, const float* __restrict__ rb2,
               float* __restrict__ rgb_out, float* __restrict__ den_out) {
    const float*  P   = ws;
    const ushort* W1T = (const ushort*)(ws + 393216);
    const ushort* W2T = W1T + 24576;
    const float*  BC  = (const float*)(W2T + 16384);

    __shared__ __align__(16) ushort Hs[4][32][136];   // per-wave [pt][k] bf16, k=0..127 (+pad)
    int wid = threadIdx.x >> 6, lane = threadIdx.x & 63;
    int c = lane & 15, g = lane >> 4;
    ushort (*H)[136] = Hs[wid];
    int gw = blockIdx.x * 4 + wid;    // 8192 waves, 4 tiles each, 32 pts/tile

    for (int it = 0; it < 4; ++it) {
        int pbase = (gw * 4 + it) * 32;

        // ---- features: lane (c,g) computes channels 8g..8g+7 of plane p for points c, c+16 ----
        FragS bfrag[2][3];
        #pragma unroll
        for (int t = 0; t < 2; ++t) {
            int pt = pbase + c + 16 * t;
            float x = points[pt * 3 + 0], y = points[pt * 3 + 1], z = points[pt * 3 + 2];
            #pragma unroll
            for (int p = 0; p < 3; ++p) {
                float cx = (p == 2) ? y : x;
                float cy = (p == 0) ? y : z;
                float ix = (cx + 1.0f) * 0.5f * 63.0f; ix = fminf(fmaxf(ix, 0.0f), 63.0f);
                float iy = (cy + 1.0f) * 0.5f * 63.0f; iy = fminf(fmaxf(iy, 0.0f), 63.0f);
                int x0 = (int)ix, y0 = (int)iy;
                int x1 = min(x0 + 1, 63), y1 = min(y0 + 1, 63);
                float wx = ix - (float)x0, wy = iy - (float)y0;
                float w00 = (1.0f - wx) * (1.0f - wy), w01 = wx * (1.0f - wy);
                float w10 = (1.0f - wx) * wy,          w11 = wx * wy;
                int b00 = ((p * 64 + y0) * 64 + x0) * 32 + 8 * g;
                int b01 = ((p * 64 + y0) * 64 + x1) * 32 + 8 * g;
                int b10 = ((p * 64 + y1) * 64 + x0) * 32 + 8 * g;
                int b11 = ((p * 64 + y1) * 64 + x1) * 32 + 8 * g;
                f32x4 a0 = *(const f32x4*)(P + b00), a1 = *(const f32x4*)(P + b00 + 4);
                f32x4 c0 = *(const f32x4*)(P + b01), c1 = *(const f32x4*)(P + b01 + 4);
                f32x4 d0 = *(const f32x4*)(P + b10), d1 = *(const f32x4*)(P + b10 + 4);
                f32x4 e0 = *(const f32x4*)(P + b11), e1 = *(const f32x4*)(P + b11 + 4);
                #pragma unroll
                for (int e = 0; e < 4; ++e) {
                    float flo = w00 * a0[e] + w01 * c0[e] + w10 * d0[e] + w11 * e0[e];
                    float fhi = w00 * a1[e] + w01 * c1[e] + w10 * d1[e] + w11 * e1[e];
                    bfrag[t][p].s[e]     = f2bf(flo);
                    bfrag[t][p].s[e + 4] = f2bf(fhi);
                }
            }
        }

        // ---- layer1: C1[j][pt] = W1cat @ feat^T, j = 16nt+4g+r, pt = c+16t ----
        float racc[3][2] = {{0.f,0.f},{0.f,0.f},{0.f,0.f}};
        #pragma unroll
        for (int nt = 0; nt < 16; ++nt) {
            FragS a1f[3];
            #pragma unroll
            for (int p = 0; p < 3; ++p)
                a1f[p].v = *(const short8*)(W1T + ((nt * 3 + p) * 64 + lane) * 8);
            f32x4 acc0 = {0.f,0.f,0.f,0.f}, acc1 = {0.f,0.f,0.f,0.f};
            #pragma unroll
            for (int p = 0; p < 3; ++p) {
                acc0 = __builtin_amdgcn_mfma_f32_16x16x32_bf16(a1f[p].v, bfrag[0][p].v, acc0, 0, 0, 0);
                acc1 = __builtin_amdgcn_mfma_f32_16x16x32_bf16(a1f[p].v, bfrag[1][p].v, acc1, 0, 0, 0);
            }
            f32x4 bb = *(const f32x4*)(BC + nt * 16 + 4 * g);
            float v0[4], v1[4];
            #pragma unroll
            for (int r = 0; r < 4; ++r) {
                v0[r] = fmaxf(acc0[r] + bb[r], 0.0f);
                v1[r] = fmaxf(acc1[r] + bb[r], 0.0f);
            }
            if (nt < 8) {
                uint2 w0; w0.x = pk2(v0[0], v0[1]); w0.y = pk2(v0[2], v0[3]);
                uint2 w1; w1.x = pk2(v1[0], v1[1]); w1.y = pk2(v1[2], v1[3]);
                *(uint2*)(&H[c][16 * nt + 4 * g])      = w0;
                *(uint2*)(&H[c + 16][16 * nt + 4 * g]) = w1;
            } else {
                #pragma unroll
                for (int o = 0; o < 3; ++o) {
                    f32x4 w = *(const f32x4*)(rW2 + o * 128 + (nt - 8) * 16 + 4 * g);
                    #pragma unroll
                    for (int r = 0; r < 4; ++r) {
                        racc[o][0] = fmaf(w[r], v0[r], racc[o][0]);
                        racc[o][1] = fmaf(w[r], v1[r], racc[o][1]);
                    }
                }
            }
        }

        // make all lanes' H writes visible before fragment reads (same wave, no barrier needed)
        asm volatile("s_waitcnt lgkmcnt(0)" ::: "memory");

        // ---- layer2 B-frags: lane (c,g) reads h[k=32kt2+8g+e][pt] = H[pt][32kt2+8g+e] ----
        FragS b2[2][4];
        #pragma unroll
        for (int t = 0; t < 2; ++t)
            #pragma unroll
            for (int kt2 = 0; kt2 < 4; ++kt2)
                b2[t][kt2].v = *(const short8*)(&H[c + 16 * t][32 * kt2 + 8 * g]);

        // ---- layer2 + density head ----
        float dacc[2] = {0.f, 0.f};
        #pragma unroll
        for (int nt2 = 0; nt2 < 8; ++nt2) {
            FragS a2f[4];
            #pragma unroll
            for (int kt2 = 0; kt2 < 4; ++kt2)
                a2f[kt2].v = *(const short8*)(W2T + ((nt2 * 4 + kt2) * 64 + lane) * 8);
            f32x4 acc0 = {0.f,0.f,0.f,0.f}, acc1 = {0.f,0.f,0.f,0.f};
            #pragma unroll
            for (int kt2 = 0; kt2 < 4; ++kt2) {
                acc0 = __builtin_amdgcn_mfma_f32_16x16x32_bf16(a2f[kt2].v, b2[0][kt2].v, acc0, 0, 0, 0);
                acc1 = __builtin_amdgcn_mfma_f32_16x16x32_bf16(a2f[kt2].v, b2[1][kt2].v, acc1, 0, 0, 0);
            }
            f32x4 bb = *(const f32x4*)(db2 + nt2 * 16 + 4 * g);
            f32x4 w3 = *(const f32x4*)(dW3 + nt2 * 16 + 4 * g);
            #pragma unroll
            for (int r = 0; r < 4; ++r) {
                dacc[0] = fmaf(w3[r], fmaxf(acc0[r] + bb[r], 0.0f), dacc[0]);
                dacc[1] = fmaf(w3[r], fmaxf(acc1[r] + bb[r], 0.0f), dacc[1]);
            }
        }

        float b3 = db3[0];
        #pragma unroll
        for (int t = 0; t < 2; ++t) {
            float v = dacc[t];
            v += __shfl_xor(v, 16, 64);
            v += __shfl_xor(v, 32, 64);
            v += b3;
            float sp = fmaxf(v, 0.0f) + log1pf(expf(-fabsf(v)));
            if (g == 0) den_out[pbase + 16 * t + c] = sp;
        }
        #pragma unroll
        for (int o = 0; o < 3; ++o)
            #pragma unroll
            for (int t = 0; t < 2; ++t) {
                float v = racc[o][t];
                v += __shfl_xor(v, 16, 64);
                v += __shfl_xor(v, 32, 64);
                v += rb2[o];
                v = 1.0f / (1.0f + expf(-v));
                if (g == 0) rgb_out[(pbase + 16 * t + c) * 3 + o] = v;
            }

        asm volatile("" ::: "memory");   // keep next tile's LDS writes after this tile's reads
    }
}

extern "C" void kernel_launch(void* const* d_in, const int* in_sizes, int n_in,
                              void* d_out, int out_size, void* d_ws, size_t ws_size,
                              hipStream_t stream) {
    const float* points = (const float*)d_in[0];
    const float* planes = (const float*)d_in[1];
    const float* dW1    = (const float*)d_in[2];
    const float* db1    = (const float*)d_in[3];
    const float* dW2    = (const float*)d_in[4];
    const float* db2    = (const float*)d_in[5];
    const float* dW3    = (const float*)d_in[6];
    const float* db3    = (const float*)d_in[7];
    const float* rW1    = (const float*)d_in[8];
    const float* rb1    = (const float*)d_in[9];
    const float* rW2    = (const float*)d_in[10];
    const float* rb2    = (const float*)d_in[11];

    float* out     = (float*)d_out;
    float* rgb_out = out;                 // 3*NPTS floats
    float* den_out = out + 3 * NPTS;      // NPTS floats
    float* ws      = (float*)d_ws;

    prepass<<<1536, 256, 0, stream>>>(planes, dW1, rW1, dW2, db1, rb1, ws);
    nerf_mfma<<<2048, 256, 0, stream>>>(points, ws, db2, db3, dW3, rW2, rb2,
                                        rgb_out, den_out);
}

// Round 3
// 1543.189 us; speedup vs baseline: 1.9967x; 1.0116x over previous
//
#include <hip/hip_runtime.h>
#include <hip/hip_bf16.h>
#include <math.h>

#define RR 64
#define CC 32
#define NPTS (4*262144)

typedef __attribute__((ext_vector_type(8))) short short8;
typedef __attribute__((ext_vector_type(4))) float f32x4;
typedef __attribute__((ext_vector_type(4))) unsigned int u32x4;

static __device__ inline ushort f2bf(float x) {
    return __builtin_bit_cast(ushort, __float2bfloat16(x));
}
static __device__ inline uint32_t pk2(float a, float b) {
    return (uint32_t)f2bf(a) | ((uint32_t)f2bf(b) << 16);
}

// ws layout:
//   float  Pcl[3*64*64*32]      @ 0            (channel-last fp32 planes [p][y][x][ch])
//   ushort W1T[16*3*64*8]       @ 393216 f     (layer1 A-frag table, [nt][p][lane][e], bf16)
//   ushort W2T[8*4*64*8]        after W1T      (layer2 A-frag table, [nt2][kt2][lane][e])
//   float  BC[256]              after W2T      (bias concat [db1|rb1])

__global__ void prepass(const float* __restrict__ planes,
                        const float* __restrict__ dW1, const float* __restrict__ rW1,
                        const float* __restrict__ dW2,
                        const float* __restrict__ db1, const float* __restrict__ rb1,
                        float* __restrict__ ws) {
    int tid = blockIdx.x * blockDim.x + threadIdx.x;
    ushort* W1T = (ushort*)(ws + 393216);
    ushort* W2T = W1T + 24576;
    float*  BC  = (float*)(W2T + 16384);

    if (tid < 3 * CC * RR * RR) {
        int x = tid % RR, y = (tid / RR) % RR, ch = (tid / (RR * RR)) % CC, p = tid / (CC * RR * RR);
        ws[((p * RR + y) * RR + x) * CC + ch] = planes[tid];
    }
    if (tid < 24576) {   // W1T: tid = ((nt*3+p)*64 + l)*8 + e
        int e = tid & 7, l = (tid >> 3) & 63, rem = tid >> 9;
        int p = rem % 3, nt = rem / 3;
        int j = nt * 16 + (l & 15);
        int k = p * 32 + (l >> 4) * 8 + e;
        float v = (j < 128) ? dW1[j * 96 + k] : rW1[(j - 128) * 96 + k];
        W1T[tid] = f2bf(v);
    }
    if (tid < 16384) {   // W2T: tid = ((nt2*4+kt2)*64 + l)*8 + e
        int e = tid & 7, l = (tid >> 3) & 63, rem = tid >> 9;
        int kt2 = rem & 3, nt2 = rem >> 2;
        int j2 = nt2 * 16 + (l & 15);
        int k = kt2 * 32 + (l >> 4) * 8 + e;
        W2T[tid] = f2bf(dW2[j2 * 128 + k]);
    }
    if (tid < 256) {
        BC[tid] = (tid < 128) ? db1[tid] : rb1[tid - 128];
    }
}

__global__ __launch_bounds__(256, 3)
void nerf_mfma(const float* __restrict__ points, const float* __restrict__ ws,
               const float* __restrict__ db2, const float* __restrict__ db3,
               const float* __restrict__ dW3,
               const float* __restrict__ rW2, const float* __restrict__ rb2,
               float* __restrict__ rgb_out, float* __restrict__ den_out) {
    const float*  P   = ws;
    const ushort* W1T = (const ushort*)(ws + 393216);
    const ushort* W2T = W1T + 24576;
    const float*  BC  = (const float*)(W2T + 16384);

    __shared__ __align__(16) ushort Hs[4][32][136];   // per-wave [pt][k] bf16, k=0..127 (+pad)
    int wid = threadIdx.x >> 6, lane = threadIdx.x & 63;
    int c = lane & 15, g = lane >> 4;
    ushort (*H)[136] = Hs[wid];
    int gw = blockIdx.x * 4 + wid;    // 8192 waves, 4 tiles each, 32 pts/tile

    for (int it = 0; it < 4; ++it) {
        int pbase = (gw * 4 + it) * 32;

        // ---- features: lane (c,g) computes channels 8g..8g+7 of plane p for points c, c+16 ----
        short8 bfrag[2][3];
        #pragma unroll
        for (int t = 0; t < 2; ++t) {
            int pt = pbase + c + 16 * t;
            float x = points[pt * 3 + 0], y = points[pt * 3 + 1], z = points[pt * 3 + 2];
            #pragma unroll
            for (int p = 0; p < 3; ++p) {
                float cx = (p == 2) ? y : x;
                float cy = (p == 0) ? y : z;
                float ix = (cx + 1.0f) * 0.5f * 63.0f; ix = fminf(fmaxf(ix, 0.0f), 63.0f);
                float iy = (cy + 1.0f) * 0.5f * 63.0f; iy = fminf(fmaxf(iy, 0.0f), 63.0f);
                int x0 = (int)ix, y0 = (int)iy;
                int x1 = min(x0 + 1, 63), y1 = min(y0 + 1, 63);
                float wx = ix - (float)x0, wy = iy - (float)y0;
                float w00 = (1.0f - wx) * (1.0f - wy), w01 = wx * (1.0f - wy);
                float w10 = (1.0f - wx) * wy,          w11 = wx * wy;
                int b00 = ((p * 64 + y0) * 64 + x0) * 32 + 8 * g;
                int b01 = ((p * 64 + y0) * 64 + x1) * 32 + 8 * g;
                int b10 = ((p * 64 + y1) * 64 + x0) * 32 + 8 * g;
                int b11 = ((p * 64 + y1) * 64 + x1) * 32 + 8 * g;
                f32x4 a0 = *(const f32x4*)(P + b00), a1 = *(const f32x4*)(P + b00 + 4);
                f32x4 c0 = *(const f32x4*)(P + b01), c1 = *(const f32x4*)(P + b01 + 4);
                f32x4 d0 = *(const f32x4*)(P + b10), d1 = *(const f32x4*)(P + b10 + 4);
                f32x4 e0 = *(const f32x4*)(P + b11), e1 = *(const f32x4*)(P + b11 + 4);
                float flo[4], fhi[4];
                #pragma unroll
                for (int e = 0; e < 4; ++e) {
                    flo[e] = w00 * a0[e] + w01 * c0[e] + w10 * d0[e] + w11 * e0[e];
                    fhi[e] = w00 * a1[e] + w01 * c1[e] + w10 * d1[e] + w11 * e1[e];
                }
                u32x4 uu;
                uu[0] = pk2(flo[0], flo[1]);
                uu[1] = pk2(flo[2], flo[3]);
                uu[2] = pk2(fhi[0], fhi[1]);
                uu[3] = pk2(fhi[2], fhi[3]);
                bfrag[t][p] = __builtin_bit_cast(short8, uu);
            }
        }

        // ---- layer1: C1[j][pt] = W1cat @ feat^T, j = 16nt+4g+r, pt = c+16t ----
        float racc[3][2] = {{0.f,0.f},{0.f,0.f},{0.f,0.f}};
        #pragma unroll
        for (int nt = 0; nt < 16; ++nt) {
            f32x4 acc0 = {0.f,0.f,0.f,0.f}, acc1 = {0.f,0.f,0.f,0.f};
            #pragma unroll
            for (int p = 0; p < 3; ++p) {
                short8 a1f = *(const short8*)(W1T + ((nt * 3 + p) * 64 + lane) * 8);
                acc0 = __builtin_amdgcn_mfma_f32_16x16x32_bf16(a1f, bfrag[0][p], acc0, 0, 0, 0);
                acc1 = __builtin_amdgcn_mfma_f32_16x16x32_bf16(a1f, bfrag[1][p], acc1, 0, 0, 0);
            }
            f32x4 bb = *(const f32x4*)(BC + nt * 16 + 4 * g);
            float v0[4], v1[4];
            #pragma unroll
            for (int r = 0; r < 4; ++r) {
                v0[r] = fmaxf(acc0[r] + bb[r], 0.0f);
                v1[r] = fmaxf(acc1[r] + bb[r], 0.0f);
            }
            if (nt < 8) {
                uint2 w0; w0.x = pk2(v0[0], v0[1]); w0.y = pk2(v0[2], v0[3]);
                uint2 w1; w1.x = pk2(v1[0], v1[1]); w1.y = pk2(v1[2], v1[3]);
                *(uint2*)(&H[c][16 * nt + 4 * g])      = w0;
                *(uint2*)(&H[c + 16][16 * nt + 4 * g]) = w1;
            } else {
                #pragma unroll
                for (int o = 0; o < 3; ++o) {
                    f32x4 w = *(const f32x4*)(rW2 + o * 128 + (nt - 8) * 16 + 4 * g);
                    #pragma unroll
                    for (int r = 0; r < 4; ++r) {
                        racc[o][0] = fmaf(w[r], v0[r], racc[o][0]);
                        racc[o][1] = fmaf(w[r], v1[r], racc[o][1]);
                    }
                }
            }
        }

        // make all lanes' H writes visible before fragment reads (same wave, no barrier needed)
        asm volatile("s_waitcnt lgkmcnt(0)" ::: "memory");

        // ---- layer2 B-frags: lane (c,g) reads h[k=32kt2+8g+e][pt] = H[pt][32kt2+8g+e] ----
        short8 b2[2][4];
        #pragma unroll
        for (int t = 0; t < 2; ++t)
            #pragma unroll
            for (int kt2 = 0; kt2 < 4; ++kt2)
                b2[t][kt2] = *(const short8*)(&H[c + 16 * t][32 * kt2 + 8 * g]);

        // ---- layer2 + density head ----
        float dacc[2] = {0.f, 0.f};
        #pragma unroll
        for (int nt2 = 0; nt2 < 8; ++nt2) {
            f32x4 acc0 = {0.f,0.f,0.f,0.f}, acc1 = {0.f,0.f,0.f,0.f};
            #pragma unroll
            for (int kt2 = 0; kt2 < 4; ++kt2) {
                short8 a2f = *(const short8*)(W2T + ((nt2 * 4 + kt2) * 64 + lane) * 8);
                acc0 = __builtin_amdgcn_mfma_f32_16x16x32_bf16(a2f, b2[0][kt2], acc0, 0, 0, 0);
                acc1 = __builtin_amdgcn_mfma_f32_16x16x32_bf16(a2f, b2[1][kt2], acc1, 0, 0, 0);
            }
            f32x4 bb = *(const f32x4*)(db2 + nt2 * 16 + 4 * g);
            f32x4 w3 = *(const f32x4*)(dW3 + nt2 * 16 + 4 * g);
            #pragma unroll
            for (int r = 0; r < 4; ++r) {
                dacc[0] = fmaf(w3[r], fmaxf(acc0[r] + bb[r], 0.0f), dacc[0]);
                dacc[1] = fmaf(w3[r], fmaxf(acc1[r] + bb[r], 0.0f), dacc[1]);
            }
        }

        float b3 = db3[0];
        #pragma unroll
        for (int t = 0; t < 2; ++t) {
            float v = dacc[t];
            v += __shfl_xor(v, 16, 64);
            v += __shfl_xor(v, 32, 64);
            v += b3;
            float sp = fmaxf(v, 0.0f) + log1pf(expf(-fabsf(v)));
            if (g == 0) den_out[pbase + 16 * t + c] = sp;
        }
        #pragma unroll
        for (int o = 0; o < 3; ++o)
            #pragma unroll
            for (int t = 0; t < 2; ++t) {
                float v = racc[o][t];
                v += __shfl_xor(v, 16, 64);
                v += __shfl_xor(v, 32, 64);
                v += rb2[o];
                v = 1.0f / (1.0f + expf(-v));
                if (g == 0) rgb_out[(pbase + 16 * t + c) * 3 + o] = v;
            }

        asm volatile("" ::: "memory");   // keep next tile's LDS writes after this tile's reads
    }
}

extern "C" void kernel_launch(void* const* d_in, const int* in_sizes, int n_in,
                              void* d_out, int out_size, void* d_ws, size_t ws_size,
                              hipStream_t stream) {
    const float* points = (const float*)d_in[0];
    const float* planes = (const float*)d_in[1];
    const float* dW1    = (const float*)d_in[2];
    const float* db1    = (const float*)d_in[3];
    const float* dW2    = (const float*)d_in[4];
    const float* db2    = (const float*)d_in[5];
    const float* dW3    = (const float*)d_in[6];
    const float* db3    = (const float*)d_in[7];
    const float* rW1    = (const float*)d_in[8];
    const float* rb1    = (const float*)d_in[9];
    const float* rW2    = (const float*)d_in[10];
    const float* rb2    = (const float*)d_in[11];

    float* out     = (float*)d_out;
    float* rgb_out = out;                 // 3*NPTS floats
    float* den_out = out + 3 * NPTS;      // NPTS floats
    float* ws      = (float*)d_ws;

    prepass<<<1536, 256, 0, stream>>>(planes, dW1, rW1, dW2, db1, rb1, ws);
    nerf_mfma<<<2048, 256, 0, stream>>>(points, ws, db2, db3, dW3, rW2, rb2,
                                        rgb_out, den_out);
}

// Round 4
// 309.158 us; speedup vs baseline: 9.9667x; 4.9916x over previous
//
#include <hip/hip_runtime.h>
#include <hip/hip_bf16.h>
#include <math.h>

#define RR 64
#define CC 32
#define NPTS (4*262144)

typedef __attribute__((ext_vector_type(8))) short short8;
typedef __attribute__((ext_vector_type(4))) float f32x4;
typedef __attribute__((ext_vector_type(4))) unsigned int u32x4;

static __device__ inline ushort f2bf(float x) {
    return __builtin_bit_cast(ushort, __float2bfloat16(x));
}
static __device__ inline uint32_t pk2(float a, float b) {
    return (uint32_t)f2bf(a) | ((uint32_t)f2bf(b) << 16);
}
static __device__ inline float relu(float x) { return fmaxf(x, 0.0f); }

// ws layout:
//   float  Pcl[3*64*64*32]      @ 0            (channel-last fp32 planes [p][y][x][ch])
//   ushort W1T[16*3*64*8]       @ 393216 f     (layer1 A-frag table, [nt][p][lane][e], bf16)
//   ushort W2T[8*4*64*8]        after W1T      (layer2 A-frag table, [nt2][kt2][lane][e])
//   float  BC[256]              after W2T      (bias concat [db1|rb1])

__global__ void prepass(const float* __restrict__ planes,
                        const float* __restrict__ dW1, const float* __restrict__ rW1,
                        const float* __restrict__ dW2,
                        const float* __restrict__ db1, const float* __restrict__ rb1,
                        float* __restrict__ ws) {
    int tid = blockIdx.x * blockDim.x + threadIdx.x;
    ushort* W1T = (ushort*)(ws + 393216);
    ushort* W2T = W1T + 24576;
    float*  BC  = (float*)(W2T + 16384);

    if (tid < 3 * CC * RR * RR) {
        int x = tid % RR, y = (tid / RR) % RR, ch = (tid / (RR * RR)) % CC, p = tid / (CC * RR * RR);
        ws[((p * RR + y) * RR + x) * CC + ch] = planes[tid];
    }
    if (tid < 24576) {   // W1T: tid = ((nt*3+p)*64 + l)*8 + e
        int e = tid & 7, l = (tid >> 3) & 63, rem = tid >> 9;
        int p = rem % 3, nt = rem / 3;
        int j = nt * 16 + (l & 15);
        int k = p * 32 + (l >> 4) * 8 + e;
        float v = (j < 128) ? dW1[j * 96 + k] : rW1[(j - 128) * 96 + k];
        W1T[tid] = f2bf(v);
    }
    if (tid < 16384) {   // W2T: tid = ((nt2*4+kt2)*64 + l)*8 + e
        int e = tid & 7, l = (tid >> 3) & 63, rem = tid >> 9;
        int kt2 = rem & 3, nt2 = rem >> 2;
        int j2 = nt2 * 16 + (l & 15);
        int k = kt2 * 32 + (l >> 4) * 8 + e;
        W2T[tid] = f2bf(dW2[j2 * 128 + k]);
    }
    if (tid < 256) {
        BC[tid] = (tid < 128) ? db1[tid] : rb1[tid - 128];
    }
}

// Bilinear-sample 8 channels (8g..8g+7) of one plane at (cx,cy), packed as a
// bf16 MFMA B-fragment for this lane. Pure scalars -> stays in registers.
static __device__ inline short8 sample_frag(const float* __restrict__ P,
                                            int plane_base, float cx, float cy, int g8) {
    float ix = (cx + 1.0f) * 31.5f; ix = fminf(fmaxf(ix, 0.0f), 63.0f);
    float iy = (cy + 1.0f) * 31.5f; iy = fminf(fmaxf(iy, 0.0f), 63.0f);
    int x0 = (int)ix, y0 = (int)iy;
    int x1 = min(x0 + 1, 63), y1 = min(y0 + 1, 63);
    float wx = ix - (float)x0, wy = iy - (float)y0;
    float w00 = (1.0f - wx) * (1.0f - wy), w01 = wx * (1.0f - wy);
    float w10 = (1.0f - wx) * wy,          w11 = wx * wy;
    int b00 = plane_base + (y0 * 64 + x0) * 32 + g8;
    int b01 = plane_base + (y0 * 64 + x1) * 32 + g8;
    int b10 = plane_base + (y1 * 64 + x0) * 32 + g8;
    int b11 = plane_base + (y1 * 64 + x1) * 32 + g8;
    f32x4 a0 = *(const f32x4*)(P + b00), a1 = *(const f32x4*)(P + b00 + 4);
    f32x4 c0 = *(const f32x4*)(P + b01), c1 = *(const f32x4*)(P + b01 + 4);
    f32x4 d0 = *(const f32x4*)(P + b10), d1 = *(const f32x4*)(P + b10 + 4);
    f32x4 e0 = *(const f32x4*)(P + b11), e1 = *(const f32x4*)(P + b11 + 4);
    float f0 = w00 * a0[0] + w01 * c0[0] + w10 * d0[0] + w11 * e0[0];
    float f1 = w00 * a0[1] + w01 * c0[1] + w10 * d0[1] + w11 * e0[1];
    float f2 = w00 * a0[2] + w01 * c0[2] + w10 * d0[2] + w11 * e0[2];
    float f3 = w00 * a0[3] + w01 * c0[3] + w10 * d0[3] + w11 * e0[3];
    float f4 = w00 * a1[0] + w01 * c1[0] + w10 * d1[0] + w11 * e1[0];
    float f5 = w00 * a1[1] + w01 * c1[1] + w10 * d1[1] + w11 * e1[1];
    float f6 = w00 * a1[2] + w01 * c1[2] + w10 * d1[2] + w11 * e1[2];
    float f7 = w00 * a1[3] + w01 * c1[3] + w10 * d1[3] + w11 * e1[3];
    u32x4 uu;
    uu[0] = pk2(f0, f1); uu[1] = pk2(f2, f3);
    uu[2] = pk2(f4, f5); uu[3] = pk2(f6, f7);
    return __builtin_bit_cast(short8, uu);
}

#define MFMA(a, b, c) __builtin_amdgcn_mfma_f32_16x16x32_bf16((a), (b), (c), 0, 0, 0)

__global__ __launch_bounds__(256, 3)
void nerf_mfma(const float* __restrict__ points, const float* __restrict__ ws,
               const float* __restrict__ db2, const float* __restrict__ db3,
               const float* __restrict__ dW3,
               const float* __restrict__ rW2, const float* __restrict__ rb2,
               float* __restrict__ rgb_out, float* __restrict__ den_out) {
    const float*  P   = ws;
    const ushort* W1T = (const ushort*)(ws + 393216);
    const ushort* W2T = W1T + 24576;
    const float*  BC  = (const float*)(W2T + 16384);

    __shared__ __align__(16) ushort Hs[4][32][136];   // per-wave [pt][k] bf16 (+pad)
    int wid = threadIdx.x >> 6, lane = threadIdx.x & 63;
    int c = lane & 15, g = lane >> 4;
    int g8 = 8 * g;
    ushort (*H)[136] = Hs[wid];
    int gw = blockIdx.x * 4 + wid;    // 8192 waves, 4 tiles each, 32 pts/tile

    for (int it = 0; it < 4; ++it) {
        int pbase = (gw * 4 + it) * 32;

        // ---- features: lane (c,g) -> channels 8g..8g+7, points A=c, B=c+16 ----
        int ptA = pbase + c, ptB = pbase + c + 16;
        float xa = points[ptA * 3 + 0], ya = points[ptA * 3 + 1], za = points[ptA * 3 + 2];
        float xb = points[ptB * 3 + 0], yb = points[ptB * 3 + 1], zb = points[ptB * 3 + 2];
        short8 bfA0 = sample_frag(P, 0,      xa, ya, g8);
        short8 bfA1 = sample_frag(P, 131072, xa, za, g8);
        short8 bfA2 = sample_frag(P, 262144, ya, za, g8);
        short8 bfB0 = sample_frag(P, 0,      xb, yb, g8);
        short8 bfB1 = sample_frag(P, 131072, xb, zb, g8);
        short8 bfB2 = sample_frag(P, 262144, yb, zb, g8);

        // ---- layer1, density half (j=0..127): -> H in LDS ----
        #pragma unroll 4
        for (int nt = 0; nt < 8; ++nt) {
            const ushort* wp = W1T + nt * 1536 + lane * 8;
            short8 a0 = *(const short8*)(wp);
            short8 a1 = *(const short8*)(wp + 512);
            short8 a2 = *(const short8*)(wp + 1024);
            f32x4 accA = {0.f,0.f,0.f,0.f}, accB = {0.f,0.f,0.f,0.f};
            accA = MFMA(a0, bfA0, accA); accB = MFMA(a0, bfB0, accB);
            accA = MFMA(a1, bfA1, accA); accB = MFMA(a1, bfB1, accB);
            accA = MFMA(a2, bfA2, accA); accB = MFMA(a2, bfB2, accB);
            f32x4 bb = *(const f32x4*)(BC + nt * 16 + 4 * g);
            uint2 wA, wB;
            wA.x = pk2(relu(accA[0] + bb[0]), relu(accA[1] + bb[1]));
            wA.y = pk2(relu(accA[2] + bb[2]), relu(accA[3] + bb[3]));
            wB.x = pk2(relu(accB[0] + bb[0]), relu(accB[1] + bb[1]));
            wB.y = pk2(relu(accB[2] + bb[2]), relu(accB[3] + bb[3]));
            *(uint2*)(&H[c][16 * nt + 4 * g])      = wA;
            *(uint2*)(&H[c + 16][16 * nt + 4 * g]) = wB;
        }

        // ---- layer1, rgb half (j=128..255): fold rW2 immediately ----
        float racc0A = 0.f, racc0B = 0.f, racc1A = 0.f, racc1B = 0.f, racc2A = 0.f, racc2B = 0.f;
        #pragma unroll 4
        for (int nt = 8; nt < 16; ++nt) {
            const ushort* wp = W1T + nt * 1536 + lane * 8;
            short8 a0 = *(const short8*)(wp);
            short8 a1 = *(const short8*)(wp + 512);
            short8 a2 = *(const short8*)(wp + 1024);
            f32x4 accA = {0.f,0.f,0.f,0.f}, accB = {0.f,0.f,0.f,0.f};
            accA = MFMA(a0, bfA0, accA); accB = MFMA(a0, bfB0, accB);
            accA = MFMA(a1, bfA1, accA); accB = MFMA(a1, bfB1, accB);
            accA = MFMA(a2, bfA2, accA); accB = MFMA(a2, bfB2, accB);
            int jo = (nt - 8) * 16 + 4 * g;
            f32x4 bb = *(const f32x4*)(BC + 128 + jo);
            f32x4 w0 = *(const f32x4*)(rW2 + jo);
            f32x4 w1 = *(const f32x4*)(rW2 + 128 + jo);
            f32x4 w2 = *(const f32x4*)(rW2 + 256 + jo);
            #pragma unroll
            for (int r = 0; r < 4; ++r) {
                float vA = relu(accA[r] + bb[r]);
                float vB = relu(accB[r] + bb[r]);
                racc0A = fmaf(w0[r], vA, racc0A); racc0B = fmaf(w0[r], vB, racc0B);
                racc1A = fmaf(w1[r], vA, racc1A); racc1B = fmaf(w1[r], vB, racc1B);
                racc2A = fmaf(w2[r], vA, racc2A); racc2B = fmaf(w2[r], vB, racc2B);
            }
        }

        // all lanes' H writes visible before fragment reads (same wave; lgkmcnt covers wave-wide ops)
        asm volatile("s_waitcnt lgkmcnt(0)" ::: "memory");

        // ---- layer2 B-frags: lane (c,g) reads h[k=32kt2+8g+e][pt] = H[pt][...] ----
        short8 b2A0 = *(const short8*)(&H[c][g8]);
        short8 b2A1 = *(const short8*)(&H[c][32 + g8]);
        short8 b2A2 = *(const short8*)(&H[c][64 + g8]);
        short8 b2A3 = *(const short8*)(&H[c][96 + g8]);
        short8 b2B0 = *(const short8*)(&H[c + 16][g8]);
        short8 b2B1 = *(const short8*)(&H[c + 16][32 + g8]);
        short8 b2B2 = *(const short8*)(&H[c + 16][64 + g8]);
        short8 b2B3 = *(const short8*)(&H[c + 16][96 + g8]);

        // ---- layer2 + density head ----
        float daccA = 0.f, daccB = 0.f;
        #pragma unroll 2
        for (int nt2 = 0; nt2 < 8; ++nt2) {
            const ushort* wp = W2T + nt2 * 2048 + lane * 8;
            short8 a0 = *(const short8*)(wp);
            short8 a1 = *(const short8*)(wp + 512);
            short8 a2 = *(const short8*)(wp + 1024);
            short8 a3 = *(const short8*)(wp + 1536);
            f32x4 accA = {0.f,0.f,0.f,0.f}, accB = {0.f,0.f,0.f,0.f};
            accA = MFMA(a0, b2A0, accA); accB = MFMA(a0, b2B0, accB);
            accA = MFMA(a1, b2A1, accA); accB = MFMA(a1, b2B1, accB);
            accA = MFMA(a2, b2A2, accA); accB = MFMA(a2, b2B2, accB);
            accA = MFMA(a3, b2A3, accA); accB = MFMA(a3, b2B3, accB);
            f32x4 bb = *(const f32x4*)(db2 + nt2 * 16 + 4 * g);
            f32x4 w3 = *(const f32x4*)(dW3 + nt2 * 16 + 4 * g);
            #pragma unroll
            for (int r = 0; r < 4; ++r) {
                daccA = fmaf(w3[r], relu(accA[r] + bb[r]), daccA);
                daccB = fmaf(w3[r], relu(accB[r] + bb[r]), daccB);
            }
        }

        // ---- heads: 4-lane-group reduce over g via shfl, then store ----
        float b3 = db3[0];
        {
            float v = daccA; v += __shfl_xor(v, 16, 64); v += __shfl_xor(v, 32, 64); v += b3;
            float sp = fmaxf(v, 0.0f) + log1pf(expf(-fabsf(v)));
            if (g == 0) den_out[pbase + c] = sp;
        }
        {
            float v = daccB; v += __shfl_xor(v, 16, 64); v += __shfl_xor(v, 32, 64); v += b3;
            float sp = fmaxf(v, 0.0f) + log1pf(expf(-fabsf(v)));
            if (g == 0) den_out[pbase + 16 + c] = sp;
        }
        {
            float v = racc0A; v += __shfl_xor(v, 16, 64); v += __shfl_xor(v, 32, 64); v += rb2[0];
            if (g == 0) rgb_out[(pbase + c) * 3 + 0] = 1.0f / (1.0f + expf(-v));
        }
        {
            float v = racc1A; v += __shfl_xor(v, 16, 64); v += __shfl_xor(v, 32, 64); v += rb2[1];
            if (g == 0) rgb_out[(pbase + c) * 3 + 1] = 1.0f / (1.0f + expf(-v));
        }
        {
            float v = racc2A; v += __shfl_xor(v, 16, 64); v += __shfl_xor(v, 32, 64); v += rb2[2];
            if (g == 0) rgb_out[(pbase + c) * 3 + 2] = 1.0f / (1.0f + expf(-v));
        }
        {
            float v = racc0B; v += __shfl_xor(v, 16, 64); v += __shfl_xor(v, 32, 64); v += rb2[0];
            if (g == 0) rgb_out[(pbase + 16 + c) * 3 + 0] = 1.0f / (1.0f + expf(-v));
        }
        {
            float v = racc1B; v += __shfl_xor(v, 16, 64); v += __shfl_xor(v, 32, 64); v += rb2[1];
            if (g == 0) rgb_out[(pbase + 16 + c) * 3 + 1] = 1.0f / (1.0f + expf(-v));
        }
        {
            float v = racc2B; v += __shfl_xor(v, 16, 64); v += __shfl_xor(v, 32, 64); v += rb2[2];
            if (g == 0) rgb_out[(pbase + 16 + c) * 3 + 2] = 1.0f / (1.0f + expf(-v));
        }

        asm volatile("" ::: "memory");   // keep next tile's LDS writes after this tile's reads
    }
}

extern "C" void kernel_launch(void* const* d_in, const int* in_sizes, int n_in,
                              void* d_out, int out_size, void* d_ws, size_t ws_size,
                              hipStream_t stream) {
    const float* points = (const float*)d_in[0];
    const float* planes = (const float*)d_in[1];
    const float* dW1    = (const float*)d_in[2];
    const float* db1    = (const float*)d_in[3];
    const float* dW2    = (const float*)d_in[4];
    const float* db2    = (const float*)d_in[5];
    const float* dW3    = (const float*)d_in[6];
    const float* db3    = (const float*)d_in[7];
    const float* rW1    = (const float*)d_in[8];
    const float* rb1    = (const float*)d_in[9];
    const float* rW2    = (const float*)d_in[10];
    const float* rb2    = (const float*)d_in[11];

    float* out     = (float*)d_out;
    float* rgb_out = out;                 // 3*NPTS floats
    float* den_out = out + 3 * NPTS;      // NPTS floats
    float* ws      = (float*)d_ws;

    prepass<<<1536, 256, 0, stream>>>(planes, dW1, rW1, dW2, db1, rb1, ws);
    nerf_mfma<<<2048, 256, 0, stream>>>(points, ws, db2, db3, dW3, rW2, rb2,
                                        rgb_out, den_out);
}

// Round 5
// 235.434 us; speedup vs baseline: 13.0877x; 1.3131x over previous
//
#include <hip/hip_runtime.h>
#include <hip/hip_bf16.h>
#include <math.h>

#define RR 64
#define CC 32
#define NPTS (4*262144)

typedef __attribute__((ext_vector_type(8))) short short8;
typedef __attribute__((ext_vector_type(4))) float f32x4;
typedef __attribute__((ext_vector_type(4))) unsigned int u32x4;

static __device__ inline ushort f2bf(float x) {
    return __builtin_bit_cast(ushort, __float2bfloat16(x));
}
static __device__ inline uint32_t pk2(float a, float b) {
    return (uint32_t)f2bf(a) | ((uint32_t)f2bf(b) << 16);
}
static __device__ inline float relu(float x) { return fmaxf(x, 0.0f); }

// ws layout:
//   float  Pcl[3*64*64*32]   @ 0          (channel-last fp32 planes [p][y][x][ch])
//   ushort W1T[24576]        @ 393216 f   (layer1 A-frag table, [nt][p][lane][e], bf16)
//   ushort W2T[16384]        follows      (layer2 A-frag table, [nt2][kt2][lane][e])
//   float  CWS[896]          follows      (BC[256] | db2[128] | dW3[128] | rW2[384])
// W1T..CWS is one contiguous 85504-byte block staged to LDS by each workgroup.

__global__ void prepass(const float* __restrict__ planes,
                        const float* __restrict__ dW1, const float* __restrict__ rW1,
                        const float* __restrict__ dW2,
                        const float* __restrict__ db1, const float* __restrict__ rb1,
                        const float* __restrict__ db2, const float* __restrict__ dW3,
                        const float* __restrict__ rW2,
                        float* __restrict__ ws) {
    int tid = blockIdx.x * blockDim.x + threadIdx.x;
    ushort* W1T = (ushort*)(ws + 393216);
    ushort* W2T = W1T + 24576;
    float*  CWS = ws + 393216 + 20480;

    if (tid < 3 * CC * RR * RR) {
        int x = tid % RR, y = (tid / RR) % RR, ch = (tid / (RR * RR)) % CC, p = tid / (CC * RR * RR);
        ws[((p * RR + y) * RR + x) * CC + ch] = planes[tid];
    }
    if (tid < 24576) {   // W1T: tid = ((nt*3+p)*64 + l)*8 + e
        int e = tid & 7, l = (tid >> 3) & 63, rem = tid >> 9;
        int p = rem % 3, nt = rem / 3;
        int j = nt * 16 + (l & 15);
        int k = p * 32 + (l >> 4) * 8 + e;
        float v = (j < 128) ? dW1[j * 96 + k] : rW1[(j - 128) * 96 + k];
        W1T[tid] = f2bf(v);
    }
    if (tid < 16384) {   // W2T: tid = ((nt2*4+kt2)*64 + l)*8 + e
        int e = tid & 7, l = (tid >> 3) & 63, rem = tid >> 9;
        int kt2 = rem & 3, nt2 = rem >> 2;
        int j2 = nt2 * 16 + (l & 15);
        int k = kt2 * 32 + (l >> 4) * 8 + e;
        W2T[tid] = f2bf(dW2[j2 * 128 + k]);
    }
    if (tid < 256) CWS[tid]       = (tid < 128) ? db1[tid] : rb1[tid - 128];
    if (tid < 128) CWS[256 + tid] = db2[tid];
    if (tid < 128) CWS[384 + tid] = dW3[tid];
    if (tid < 384) CWS[512 + tid] = rW2[tid];
}

// Bilinear-sample 8 channels (8g..8g+7) of one plane at (cx,cy), packed as a
// bf16 MFMA B-fragment for this lane. Pure named scalars -> registers.
static __device__ inline short8 sample_frag(const float* __restrict__ P,
                                            int plane_base, float cx, float cy, int g8) {
    float ix = (cx + 1.0f) * 31.5f; ix = fminf(fmaxf(ix, 0.0f), 63.0f);
    float iy = (cy + 1.0f) * 31.5f; iy = fminf(fmaxf(iy, 0.0f), 63.0f);
    int x0 = (int)ix, y0 = (int)iy;
    int x1 = min(x0 + 1, 63), y1 = min(y0 + 1, 63);
    float wx = ix - (float)x0, wy = iy - (float)y0;
    float w00 = (1.0f - wx) * (1.0f - wy), w01 = wx * (1.0f - wy);
    float w10 = (1.0f - wx) * wy,          w11 = wx * wy;
    int b00 = plane_base + (y0 * 64 + x0) * 32 + g8;
    int b01 = plane_base + (y0 * 64 + x1) * 32 + g8;
    int b10 = plane_base + (y1 * 64 + x0) * 32 + g8;
    int b11 = plane_base + (y1 * 64 + x1) * 32 + g8;
    f32x4 a0 = *(const f32x4*)(P + b00), a1 = *(const f32x4*)(P + b00 + 4);
    f32x4 c0 = *(const f32x4*)(P + b01), c1 = *(const f32x4*)(P + b01 + 4);
    f32x4 d0 = *(const f32x4*)(P + b10), d1 = *(const f32x4*)(P + b10 + 4);
    f32x4 e0 = *(const f32x4*)(P + b11), e1 = *(const f32x4*)(P + b11 + 4);
    float f0 = w00 * a0[0] + w01 * c0[0] + w10 * d0[0] + w11 * e0[0];
    float f1 = w00 * a0[1] + w01 * c0[1] + w10 * d0[1] + w11 * e0[1];
    float f2 = w00 * a0[2] + w01 * c0[2] + w10 * d0[2] + w11 * e0[2];
    float f3 = w00 * a0[3] + w01 * c0[3] + w10 * d0[3] + w11 * e0[3];
    float f4 = w00 * a1[0] + w01 * c1[0] + w10 * d1[0] + w11 * e1[0];
    float f5 = w00 * a1[1] + w01 * c1[1] + w10 * d1[1] + w11 * e1[1];
    float f6 = w00 * a1[2] + w01 * c1[2] + w10 * d1[2] + w11 * e1[2];
    float f7 = w00 * a1[3] + w01 * c1[3] + w10 * d1[3] + w11 * e1[3];
    u32x4 uu;
    uu[0] = pk2(f0, f1); uu[1] = pk2(f2, f3);
    uu[2] = pk2(f4, f5); uu[3] = pk2(f6, f7);
    return __builtin_bit_cast(short8, uu);
}

#define MFMA(a, b, c) __builtin_amdgcn_mfma_f32_16x16x32_bf16((a), (b), (c), 0, 0, 0)

__global__ __launch_bounds__(512, 2)
void nerf_mfma(const float* __restrict__ points, const float* __restrict__ ws,
               const float* __restrict__ db3g, const float* __restrict__ rb2g,
               float* __restrict__ rgb_out, float* __restrict__ den_out) {
    // LDS: weight tables + consts (85504 B) + per-wave H (8*32*136*2 = 69632 B) = 155136 B
    __shared__ __align__(16) ushort SB[42752];
    __shared__ __align__(16) ushort Hs[8][32][136];

    const float* P = ws;
    int tid = threadIdx.x;

    // ---- stage weight tables + consts into LDS (once per block) ----
    {
        const u32x4* src = (const u32x4*)(ws + 393216);
        u32x4* dst = (u32x4*)SB;
        #pragma unroll 2
        for (int j = tid; j < 5344; j += 512) dst[j] = src[j];
    }
    __syncthreads();

    const ushort* W1L = SB;                       // 24576 ushorts
    const ushort* W2L = SB + 24576;               // 16384 ushorts
    const float*  Cl  = (const float*)(SB + 40960);  // BC|db2|dW3|rW2

    int wid = tid >> 6, lane = tid & 63;
    int c = lane & 15, g = lane >> 4;
    int g8 = 8 * g;
    ushort (*H)[136] = Hs[wid];
    int gw = blockIdx.x * 8 + wid;     // 16384 waves, 2 tiles each, 32 pts/tile

    float b3 = db3g[0];
    float rb0 = rb2g[0], rb1v = rb2g[1], rb2v = rb2g[2];

    for (int it = 0; it < 2; ++it) {
        int pbase = (gw * 2 + it) * 32;

        // ---- features: lane (c,g) -> channels 8g..8g+7, points A=c, B=c+16 ----
        int ptA = pbase + c, ptB = pbase + c + 16;
        float xa = points[ptA * 3 + 0], ya = points[ptA * 3 + 1], za = points[ptA * 3 + 2];
        float xb = points[ptB * 3 + 0], yb = points[ptB * 3 + 1], zb = points[ptB * 3 + 2];
        short8 bfA0 = sample_frag(P, 0,      xa, ya, g8);
        short8 bfA1 = sample_frag(P, 131072, xa, za, g8);
        short8 bfA2 = sample_frag(P, 262144, ya, za, g8);
        short8 bfB0 = sample_frag(P, 0,      xb, yb, g8);
        short8 bfB1 = sample_frag(P, 131072, xb, zb, g8);
        short8 bfB2 = sample_frag(P, 262144, yb, zb, g8);

        // ---- layer1, density half (j=0..127): -> H in LDS ----
        #pragma unroll 4
        for (int nt = 0; nt < 8; ++nt) {
            const ushort* wp = W1L + nt * 1536 + lane * 8;
            short8 a0 = *(const short8*)(wp);
            short8 a1 = *(const short8*)(wp + 512);
            short8 a2 = *(const short8*)(wp + 1024);
            f32x4 accA = {0.f,0.f,0.f,0.f}, accB = {0.f,0.f,0.f,0.f};
            accA = MFMA(a0, bfA0, accA); accB = MFMA(a0, bfB0, accB);
            accA = MFMA(a1, bfA1, accA); accB = MFMA(a1, bfB1, accB);
            accA = MFMA(a2, bfA2, accA); accB = MFMA(a2, bfB2, accB);
            f32x4 bb = *(const f32x4*)(Cl + nt * 16 + 4 * g);
            uint2 wA, wB;
            wA.x = pk2(relu(accA[0] + bb[0]), relu(accA[1] + bb[1]));
            wA.y = pk2(relu(accA[2] + bb[2]), relu(accA[3] + bb[3]));
            wB.x = pk2(relu(accB[0] + bb[0]), relu(accB[1] + bb[1]));
            wB.y = pk2(relu(accB[2] + bb[2]), relu(accB[3] + bb[3]));
            *(uint2*)(&H[c][16 * nt + 4 * g])      = wA;
            *(uint2*)(&H[c + 16][16 * nt + 4 * g]) = wB;
        }

        // ---- layer1, rgb half (j=128..255): fold rW2 immediately ----
        float racc0A = 0.f, racc0B = 0.f, racc1A = 0.f, racc1B = 0.f, racc2A = 0.f, racc2B = 0.f;
        #pragma unroll 4
        for (int nt = 8; nt < 16; ++nt) {
            const ushort* wp = W1L + nt * 1536 + lane * 8;
            short8 a0 = *(const short8*)(wp);
            short8 a1 = *(const short8*)(wp + 512);
            short8 a2 = *(const short8*)(wp + 1024);
            f32x4 accA = {0.f,0.f,0.f,0.f}, accB = {0.f,0.f,0.f,0.f};
            accA = MFMA(a0, bfA0, accA); accB = MFMA(a0, bfB0, accB);
            accA = MFMA(a1, bfA1, accA); accB = MFMA(a1, bfB1, accB);
            accA = MFMA(a2, bfA2, accA); accB = MFMA(a2, bfB2, accB);
            int jo = (nt - 8) * 16 + 4 * g;
            f32x4 bb = *(const f32x4*)(Cl + 128 + jo);
            f32x4 w0 = *(const f32x4*)(Cl + 512 + jo);
            f32x4 w1 = *(const f32x4*)(Cl + 640 + jo);
            f32x4 w2 = *(const f32x4*)(Cl + 768 + jo);
            #pragma unroll
            for (int r = 0; r < 4; ++r) {
                float vA = relu(accA[r] + bb[r]);
                float vB = relu(accB[r] + bb[r]);
                racc0A = fmaf(w0[r], vA, racc0A); racc0B = fmaf(w0[r], vB, racc0B);
                racc1A = fmaf(w1[r], vA, racc1A); racc1B = fmaf(w1[r], vB, racc1B);
                racc2A = fmaf(w2[r], vA, racc2A); racc2B = fmaf(w2[r], vB, racc2B);
            }
        }

        // all lanes' H writes visible before cross-lane fragment reads (same wave)
        asm volatile("s_waitcnt lgkmcnt(0)" ::: "memory");
        __builtin_amdgcn_sched_barrier(0);

        // ---- layer2 B-frags: lane (c,g) reads h[k=32kt2+8g+e][pt] = H[pt][...] ----
        short8 b2A0 = *(const short8*)(&H[c][g8]);
        short8 b2A1 = *(const short8*)(&H[c][32 + g8]);
        short8 b2A2 = *(const short8*)(&H[c][64 + g8]);
        short8 b2A3 = *(const short8*)(&H[c][96 + g8]);
        short8 b2B0 = *(const short8*)(&H[c + 16][g8]);
        short8 b2B1 = *(const short8*)(&H[c + 16][32 + g8]);
        short8 b2B2 = *(const short8*)(&H[c + 16][64 + g8]);
        short8 b2B3 = *(const short8*)(&H[c + 16][96 + g8]);

        // ---- layer2 + density head ----
        float daccA = 0.f, daccB = 0.f;
        #pragma unroll 2
        for (int nt2 = 0; nt2 < 8; ++nt2) {
            const ushort* wp = W2L + nt2 * 2048 + lane * 8;
            short8 a0 = *(const short8*)(wp);
            short8 a1 = *(const short8*)(wp + 512);
            short8 a2 = *(const short8*)(wp + 1024);
            short8 a3 = *(const short8*)(wp + 1536);
            f32x4 accA = {0.f,0.f,0.f,0.f}, accB = {0.f,0.f,0.f,0.f};
            accA = MFMA(a0, b2A0, accA); accB = MFMA(a0, b2B0, accB);
            accA = MFMA(a1, b2A1, accA); accB = MFMA(a1, b2B1, accB);
            accA = MFMA(a2, b2A2, accA); accB = MFMA(a2, b2B2, accB);
            accA = MFMA(a3, b2A3, accA); accB = MFMA(a3, b2B3, accB);
            f32x4 bb = *(const f32x4*)(Cl + 256 + nt2 * 16 + 4 * g);
            f32x4 w3 = *(const f32x4*)(Cl + 384 + nt2 * 16 + 4 * g);
            #pragma unroll
            for (int r = 0; r < 4; ++r) {
                daccA = fmaf(w3[r], relu(accA[r] + bb[r]), daccA);
                daccB = fmaf(w3[r], relu(accB[r] + bb[r]), daccB);
            }
        }

        // ---- heads: reduce over g via shfl, then store ----
        {
            float v = daccA; v += __shfl_xor(v, 16, 64); v += __shfl_xor(v, 32, 64); v += b3;
            float sp = fmaxf(v, 0.0f) + log1pf(expf(-fabsf(v)));
            if (g == 0) den_out[pbase + c] = sp;
        }
        {
            float v = daccB; v += __shfl_xor(v, 16, 64); v += __shfl_xor(v, 32, 64); v += b3;
            float sp = fmaxf(v, 0.0f) + log1pf(expf(-fabsf(v)));
            if (g == 0) den_out[pbase + 16 + c] = sp;
        }
        {
            float v = racc0A; v += __shfl_xor(v, 16, 64); v += __shfl_xor(v, 32, 64); v += rb0;
            if (g == 0) rgb_out[(pbase + c) * 3 + 0] = 1.0f / (1.0f + expf(-v));
        }
        {
            float v = racc1A; v += __shfl_xor(v, 16, 64); v += __shfl_xor(v, 32, 64); v += rb1v;
            if (g == 0) rgb_out[(pbase + c) * 3 + 1] = 1.0f / (1.0f + expf(-v));
        }
        {
            float v = racc2A; v += __shfl_xor(v, 16, 64); v += __shfl_xor(v, 32, 64); v += rb2v;
            if (g == 0) rgb_out[(pbase + c) * 3 + 2] = 1.0f / (1.0f + expf(-v));
        }
        {
            float v = racc0B; v += __shfl_xor(v, 16, 64); v += __shfl_xor(v, 32, 64); v += rb0;
            if (g == 0) rgb_out[(pbase + 16 + c) * 3 + 0] = 1.0f / (1.0f + expf(-v));
        }
        {
            float v = racc1B; v += __shfl_xor(v, 16, 64); v += __shfl_xor(v, 32, 64); v += rb1v;
            if (g == 0) rgb_out[(pbase + 16 + c) * 3 + 1] = 1.0f / (1.0f + expf(-v));
        }
        {
            float v = racc2B; v += __shfl_xor(v, 16, 64); v += __shfl_xor(v, 32, 64); v += rb2v;
            if (g == 0) rgb_out[(pbase + 16 + c) * 3 + 2] = 1.0f / (1.0f + expf(-v));
        }

        asm volatile("" ::: "memory");   // keep next tile's LDS writes after this tile's reads
    }
}

extern "C" void kernel_launch(void* const* d_in, const int* in_sizes, int n_in,
                              void* d_out, int out_size, void* d_ws, size_t ws_size,
                              hipStream_t stream) {
    const float* points = (const float*)d_in[0];
    const float* planes = (const float*)d_in[1];
    const float* dW1    = (const float*)d_in[2];
    const float* db1    = (const float*)d_in[3];
    const float* dW2    = (const float*)d_in[4];
    const float* db2    = (const float*)d_in[5];
    const float* dW3    = (const float*)d_in[6];
    const float* db3    = (const float*)d_in[7];
    const float* rW1    = (const float*)d_in[8];
    const float* rb1    = (const float*)d_in[9];
    const float* rW2    = (const float*)d_in[10];
    const float* rb2    = (const float*)d_in[11];

    float* out     = (float*)d_out;
    float* rgb_out = out;                 // 3*NPTS floats
    float* den_out = out + 3 * NPTS;      // NPTS floats
    float* ws      = (float*)d_ws;

    prepass<<<1536, 256, 0, stream>>>(planes, dW1, rW1, dW2, db1, rb1,
                                      db2, dW3, rW2, ws);
    nerf_mfma<<<2048, 512, 0, stream>>>(points, ws, db3, rb2, rgb_out, den_out);
}